// Round 8
// baseline (4805.814 us; speedup 1.0000x reference)
//
#include <hip/hip_runtime.h>

// AttentionRnnBlock: N=16, T=2048, H=512.
// q|k|v = cat(x_t,h_t) @ W?.T + b? ; w=sigmoid(q*k); h' = (1-w)h + w tanh(v)
//
// Persistent cooperative kernel, 256 WGs x 512 threads, 1 WG/CU.
//  - 8 groups x 32 WGs; group g owns batches {2g,2g+1}.
//  - h exchange: PARITY DOUBLE-BUFFERED tagged 8B words ex[t&1][g][1024],
//    word = (t)<<32 | float_bits, stored with relaxed agent atomics.
//    Round 7's single-buffer version deadlocked: a writer one step ahead
//    overwrites tag t with t+1 before a slow reader polls it (lost wakeup).
//    With parity buffers, slot [t&1] is next overwritten only by tag t+2,
//    whose store is gated (via the writer's t+1 spin -> reader's WG t+1
//    stores -> reader passing step t) on the reader's own progress.
//  - hs LDS stage is parity double-buffered too: one barrier per step is
//    WAR-safe (step t+1 writes hs[(t+1)&1] while stragglers read hs[t&1]).
//  - Weights (96 floats/thread) pinned in AGPRs via v_accvgpr_write/read
//    (rounds 2-6: allocator spills source-level pins; asm "a" class can't).
#define N_B 16
#define T_S 2048
#define H_D 512
#define TH_F ((size_t)T_S * H_D)
#define NTH ((size_t)N_B * TH_F)
#define NGROUP 8
#define WPG 32
#define THREADS 512
#define EXG 1024                 // words per group per parity
#define EXP_W (NGROUP * EXG)     // words per parity plane

#define STASH(dst, src) asm volatile("v_accvgpr_write_b32 %0, %1" : "=a"(dst) : "v"(src))
#define FETCH(dst, src) asm volatile("v_accvgpr_read_b32 %0, %1" : "=v"(dst) : "a"(src))

__global__ __launch_bounds__(THREADS, 1) void rnn_persist(
    const float* __restrict__ x,
    const float* __restrict__ hidden,
    const float* __restrict__ Wq, const float* __restrict__ bq,
    const float* __restrict__ Wk, const float* __restrict__ bk,
    const float* __restrict__ Wv, const float* __restrict__ bv,
    float* __restrict__ out,
    unsigned long long* __restrict__ ex)
{
    const int tid  = threadIdx.x;
    const int lane = tid & 63;
    const int wv   = tid >> 6;          // wave 0..7
    const int g    = blockIdx.x & 7;    // group
    const int wm   = blockIdx.x >> 3;   // member 0..31
    const int b0 = 2 * g, b1 = 2 * g + 1;
    const int jA = wm * 16 + 2 * wv;

    __shared__ __align__(16) float hs[2][2][H_D];   // [parity][batch][H], 8 KB

    // ---- load weights once, stash all 96 floats into AGPRs
    float awx[2][3][8], awh[2][3][8];
    #pragma unroll
    for (int r = 0; r < 2; ++r) {
        const int j = jA + r;
        #pragma unroll
        for (int m = 0; m < 3; ++m) {
            const float* W = (m == 0) ? Wq : (m == 1) ? Wk : Wv;
            const float* base = W + (size_t)j * 1024 + lane * 8;
            float4 x0 = *(const float4*)(base);
            float4 x1 = *(const float4*)(base + 4);
            float4 h0 = *(const float4*)(base + 512);
            float4 h1 = *(const float4*)(base + 516);
            STASH(awx[r][m][0], x0.x); STASH(awx[r][m][1], x0.y);
            STASH(awx[r][m][2], x0.z); STASH(awx[r][m][3], x0.w);
            STASH(awx[r][m][4], x1.x); STASH(awx[r][m][5], x1.y);
            STASH(awx[r][m][6], x1.z); STASH(awx[r][m][7], x1.w);
            STASH(awh[r][m][0], h0.x); STASH(awh[r][m][1], h0.y);
            STASH(awh[r][m][2], h0.z); STASH(awh[r][m][3], h0.w);
            STASH(awh[r][m][4], h1.x); STASH(awh[r][m][5], h1.y);
            STASH(awh[r][m][6], h1.z); STASH(awh[r][m][7], h1.w);
        }
    }

    // writer-lane (lane<4) constants: bit0 = batch, bit1 = row
    const int jw = jA + ((lane >> 1) & 1);
    const int bw = (lane & 1) ? b1 : b0;
    const float bqw = bq[jw], bkw = bk[jw], bvw = bv[jw];
    float ho = hidden[bw * H_D + jw];

    // h staging map: thread -> (batch half, float2 #u)
    const int h_nb  = tid >> 8;
    const int h_pos = (tid & 255) * 2;
    const int h_b   = h_nb ? b1 : b0;

    // exchange pointers (both parities)
    unsigned long long* const exg0 = ex + (size_t)g * EXG;
    unsigned long long* const exg1 = exg0 + EXP_W;
    unsigned long long* const sp0_p0 = exg0 + (size_t)tid * 2;  // own words
    unsigned long long* const sp0_p1 = exg1 + (size_t)tid * 2;
    const int exw_idx = (lane & 1) * 512 + jw;                  // writer word

    // ---- prologue: h_0 -> hs[0]; out[:,0,:] = h_0 (group's first WG only)
    {
        float v0 = hidden[h_b * H_D + h_pos];
        float v1 = hidden[h_b * H_D + h_pos + 1];
        *(float2*)&hs[0][h_nb][h_pos] = make_float2(v0, v1);
        if (wm == 0) {
            out[(size_t)h_b * TH_F + h_pos]     = v0;
            out[(size_t)h_b * TH_F + h_pos + 1] = v1;
        }
    }
    __syncthreads();

    // x lane-slice pointers (float4 granularity) + first prefetch
    const float4* xb0 = (const float4*)(x + (size_t)b0 * TH_F) + lane * 2;
    const float4* xb1 = (const float4*)(x + (size_t)b1 * TH_F) + lane * 2;
    float ax[2][8];
    {
        float4 a = xb0[0], b = xb0[1], c = xb1[0], d = xb1[1];
        ax[0][0]=a.x; ax[0][1]=a.y; ax[0][2]=a.z; ax[0][3]=a.w;
        ax[0][4]=b.x; ax[0][5]=b.y; ax[0][6]=b.z; ax[0][7]=b.w;
        ax[1][0]=c.x; ax[1][1]=c.y; ax[1][2]=c.z; ax[1][3]=c.w;
        ax[1][4]=d.x; ax[1][5]=d.y; ax[1][6]=d.z; ax[1][7]=d.w;
    }

    for (int t = 0; t < T_S; ++t) {
        const bool do_next = (t + 1 < T_S);
        const int  p  = t & 1;
        unsigned long long* const spA = p ? sp0_p1 : sp0_p0;

        // ---- issue own-word polls EARLY (latency hides under x-part)
        unsigned long long w0 = 0, w1 = 0;
        if (t > 0) {
            w0 = __hip_atomic_load(spA,     __ATOMIC_RELAXED, __HIP_MEMORY_SCOPE_AGENT);
            w1 = __hip_atomic_load(spA + 1, __ATOMIC_RELAXED, __HIP_MEMORY_SCOPE_AGENT);
        }

        // ---- x-part: 48 AGPR fetches + 96 FMAs (h-independent)
        float acc[2][3][2];
        #pragma unroll
        for (int r = 0; r < 2; ++r)
            #pragma unroll
            for (int m = 0; m < 3; ++m) {
                float wreg[8];
                #pragma unroll
                for (int c = 0; c < 8; ++c) FETCH(wreg[c], awx[r][m][c]);
                float s0 = 0.f, s1 = 0.f;
                #pragma unroll
                for (int c = 0; c < 8; ++c) {
                    s0 = fmaf(wreg[c], ax[0][c], s0);
                    s1 = fmaf(wreg[c], ax[1][c], s1);
                }
                acc[r][m][0] = s0; acc[r][m][1] = s1;
            }

        // ---- prefetch x_{t+1} (in flight across the wait)
        if (do_next) {
            const size_t o = (size_t)(t + 1) * 128;
            float4 a = xb0[o], b = xb0[o + 1], c = xb1[o], d = xb1[o + 1];
            ax[0][0]=a.x; ax[0][1]=a.y; ax[0][2]=a.z; ax[0][3]=a.w;
            ax[0][4]=b.x; ax[0][5]=b.y; ax[0][6]=b.z; ax[0][7]=b.w;
            ax[1][0]=c.x; ax[1][1]=c.y; ax[1][2]=c.z; ax[1][3]=c.w;
            ax[1][4]=d.x; ax[1][5]=d.y; ax[1][6]=d.z; ax[1][7]=d.w;
        }

        // ---- spin on own tagged words; stage h_t into hs[p]; ONE barrier
        if (t > 0) {
            const unsigned tt = (unsigned)t;
            while ((((unsigned)(w0 >> 32)) != tt) |
                   (((unsigned)(w1 >> 32)) != tt)) {
                w0 = __hip_atomic_load(spA,     __ATOMIC_RELAXED, __HIP_MEMORY_SCOPE_AGENT);
                w1 = __hip_atomic_load(spA + 1, __ATOMIC_RELAXED, __HIP_MEMORY_SCOPE_AGENT);
            }
            union { unsigned u; float f; } c0, c1;
            c0.u = (unsigned)w0; c1.u = (unsigned)w1;
            *(float2*)&hs[p][h_nb][h_pos] = make_float2(c0.f, c1.f);
            __syncthreads();
        }

        // ---- h-part: 48 AGPR fetches + 96 FMAs (reads hs[p])
        float hbv[2][8];
        #pragma unroll
        for (int nb = 0; nb < 2; ++nb) {
            const float4* hp = (const float4*)&hs[p][nb][0] + lane * 2;
            float4 a0 = hp[0], a1 = hp[1];
            hbv[nb][0]=a0.x; hbv[nb][1]=a0.y; hbv[nb][2]=a0.z; hbv[nb][3]=a0.w;
            hbv[nb][4]=a1.x; hbv[nb][5]=a1.y; hbv[nb][6]=a1.z; hbv[nb][7]=a1.w;
        }
        #pragma unroll
        for (int r = 0; r < 2; ++r)
            #pragma unroll
            for (int m = 0; m < 3; ++m) {
                float wreg[8];
                #pragma unroll
                for (int c = 0; c < 8; ++c) FETCH(wreg[c], awh[r][m][c]);
                float s0 = acc[r][m][0], s1 = acc[r][m][1];
                #pragma unroll
                for (int c = 0; c < 8; ++c) {
                    s0 = fmaf(wreg[c], hbv[0][c], s0);
                    s1 = fmaf(wreg[c], hbv[1][c], s1);
                }
                acc[r][m][0] = s0; acc[r][m][1] = s1;
            }

        // ---- split-butterfly reduce: 21 shfl
        const bool lb0 = (lane & 1) != 0;   // batch bit
        const bool lb1 = (lane & 2) != 0;   // row bit
        float a6[2][3];
        #pragma unroll
        for (int r = 0; r < 2; ++r)
            #pragma unroll
            for (int m = 0; m < 3; ++m) {
                float keep = lb0 ? acc[r][m][1] : acc[r][m][0];
                float send = lb0 ? acc[r][m][0] : acc[r][m][1];
                a6[r][m] = keep + __shfl_xor(send, 1);
            }
        float a3[3];
        #pragma unroll
        for (int m = 0; m < 3; ++m) {
            float keep = lb1 ? a6[1][m] : a6[0][m];
            float send = lb1 ? a6[0][m] : a6[1][m];
            a3[m] = keep + __shfl_xor(send, 2);
        }
        #pragma unroll
        for (int s = 4; s < 64; s <<= 1) {
            a3[0] += __shfl_xor(a3[0], s);
            a3[1] += __shfl_xor(a3[1], s);
            a3[2] += __shfl_xor(a3[2], s);
        }

        // ---- gate + h_{t+1} stores (writer lanes 0..3)
        if (lane < 4) {
            const float q = a3[0] + bqw;
            const float k = a3[1] + bkw;
            const float v = a3[2] + bvw;
            const float e  = __expf(-q * k);
            const float w  = __builtin_amdgcn_rcpf(1.f + e);
            const float ev = __expf(2.f * v);
            const float th = 1.f - 2.f * __builtin_amdgcn_rcpf(ev + 1.f);
            const float hn = fmaf(w, th - ho, ho);
            if (do_next) {
                out[(size_t)bw * TH_F + (size_t)(t + 1) * H_D + jw] = hn;  // output only
                union { float f; unsigned u; } cv; cv.f = hn;
                unsigned long long* exwP = ((t + 1) & 1) ? (exg1 + exw_idx)
                                                         : (exg0 + exw_idx);
                __hip_atomic_store(exwP,
                    (((unsigned long long)(unsigned)(t + 1)) << 32) | cv.u,
                    __ATOMIC_RELAXED, __HIP_MEMORY_SCOPE_AGENT);           // data+signal
            } else {
                out[NTH + (size_t)bw * H_D + jw] = hn;                     // h_final tail
            }
            ho = hn;
        }
        // no end barrier: parity-buffered hs + the next spin make it WAR-safe.
    }
}

extern "C" void kernel_launch(void* const* d_in, const int* in_sizes, int n_in,
                              void* d_out, int out_size, void* d_ws, size_t ws_size,
                              hipStream_t stream) {
    const float* x      = (const float*)d_in[0];
    const float* hidden = (const float*)d_in[1];
    const float* Wq     = (const float*)d_in[2];
    const float* bq     = (const float*)d_in[3];
    const float* Wk     = (const float*)d_in[4];
    const float* bk     = (const float*)d_in[5];
    const float* Wv     = (const float*)d_in[6];
    const float* bv     = (const float*)d_in[7];
    float* out = (float*)d_out;
    unsigned long long* ex = (unsigned long long*)d_ws;  // 2 x 8 x 1024 words

    // Clear tags every call: replay-safe (stale tags would satisfy spins
    // instantly and break both correctness and the timing contract).
    hipMemsetAsync(ex, 0, 2 * EXP_W * sizeof(unsigned long long), stream);

    void* args[] = { (void*)&x, (void*)&hidden,
                     (void*)&Wq, (void*)&bq, (void*)&Wk, (void*)&bk,
                     (void*)&Wv, (void*)&bv, (void*)&out, (void*)&ex };
    hipLaunchCooperativeKernel((const void*)rnn_persist,
                               dim3(NGROUP * WPG), dim3(THREADS),
                               args, 0, stream);
}